// Round 2
// baseline (1418.615 us; speedup 1.0000x reference)
//
#include <hip/hip_runtime.h>

#define B_ 4096
#define S_ 2048
#define H_ 8

__device__ __forceinline__ float rcp_(float x)  { return __builtin_amdgcn_rcpf(x); }
__device__ __forceinline__ float exp2_(float x) { return __builtin_amdgcn_exp2f(x); }
// sigmoid(x) = 1/(1+2^(-x*log2e));  tanh(x) = 1 - 2/(1+2^(2x*log2e))
// both saturate cleanly at +-inf (exp2->0 or inf; rcp(inf)=0) — no NaN possible
__device__ __forceinline__ float tanh_(float x) {
    return fmaf(-2.0f, rcp_(1.0f + exp2_(2.88539008f * x)), 1.0f);
}

__device__ __forceinline__ void ld8(const float* p, float* o) {
    float4 a = *(const float4*)p;
    float4 b = *(const float4*)(p + 4);
    o[0] = a.x; o[1] = a.y; o[2] = a.z; o[3] = a.w;
    o[4] = b.x; o[5] = b.y; o[6] = b.z; o[7] = b.w;
}

// 16 lanes per batch element. sub = lane&15, j = sub&7, half = sub>>3.
// half==0 lane owns gates i[j] (row j)    and g~[j] (row 16+j)
// half==1 lane owns gates f[j] (row 8+j)  and o[j]  (row 24+j)
// c[j], h[j] computed redundantly in both halves after one shfl_xor(8) exchange.
__global__ __launch_bounds__(64) void lstm_main(
    const float* __restrict__ seq, const int* __restrict__ lengths,
    const float* __restrict__ Wih0, const float* __restrict__ Whh0,
    const float* __restrict__ bih0, const float* __restrict__ bhh0,
    const float* __restrict__ Wih1, const float* __restrict__ Whh1,
    const float* __restrict__ bih1, const float* __restrict__ bhh1,
    float* __restrict__ yout)
{
    const int tid  = threadIdx.x;
    const int grp  = tid >> 4;
    const int sub  = tid & 15;
    const int j    = sub & 7;
    const int half = sub >> 3;
    const int b    = blockIdx.x * 4 + grp;
    const int base = tid & 48;            // group base lane for shfl

    const int gA = half * 8 + j;          // i or f row
    const int gB = 16 + half * 8 + j;     // g~ or o row

    // ---- stage weights into registers ----
    float wi0A[8], wi0B[8], wh0A[8], wh0B[8];
    float wi1A[8], wi1B[8], wh1A[8], wh1B[8];
    ld8(Wih0 + gA * 8, wi0A);
    ld8(Wih0 + gB * 8, wi0B);
    ld8(Whh0 + gA * 8, wh0A);
    ld8(Whh0 + gB * 8, wh0B);
    ld8(Wih1 + gA * 8, wi1A);
    ld8(Wih1 + gB * 8, wi1B);
    ld8(Whh1 + gA * 8, wh1A);
    ld8(Whh1 + gB * 8, wh1B);
    const float bs0A = bih0[gA] + bhh0[gA];
    const float bs0B = bih0[gB] + bhh0[gB];
    const float bs1A = bih1[gA] + bhh1[gA];
    const float bs1B = bih1[gB] + bhh1[gB];

    // gate A is always sigmoid. gate B: tanh for half==0 (g~), sigmoid for half==1 (o).
    // unified: act(x) = a * rcp(1 + exp2(s*x)) + c
    const float sB = half ? -1.44269504f : 2.88539008f;
    const float aB = half ?  1.0f        : -2.0f;
    const float cB = half ?  0.0f        :  1.0f;

    const int len = lengths[b];
    int maxlen = len;
    maxlen = max(maxlen, __shfl_xor(maxlen, 16));
    maxlen = max(maxlen, __shfl_xor(maxlen, 32));   // wave-uniform loop bound

    float h0v[8], h1v[8];
    #pragma unroll
    for (int k = 0; k < 8; ++k) { h0v[k] = 0.0f; h1v[k] = 0.0f; }
    float c0 = 0.0f, c1 = 0.0f, ysave = 0.0f;

    const float* xbase = seq + (size_t)b * S_ * 8;
    float xf[8];
    ld8(xbase, xf);                                  // t = 0

    for (int t = 0; t < maxlen; ++t) {
        // prefetch next x (state-independent; latency hidden behind compute)
        const int tn = (t + 1 < S_) ? (t + 1) : (S_ - 1);
        float xn[8];
        ld8(xbase + (size_t)tn * 8, xn);

        // ---------------- layer 0 ----------------
        float accA = bs0A, accB = bs0B;
        #pragma unroll
        for (int k = 0; k < 8; ++k) {
            accA = fmaf(wi0A[k], xf[k], accA);
            accB = fmaf(wi0B[k], xf[k], accB);
        }
        #pragma unroll
        for (int k = 0; k < 8; ++k) {
            accA = fmaf(wh0A[k], h0v[k], accA);
            accB = fmaf(wh0B[k], h0v[k], accB);
        }
        float vA = rcp_(1.0f + exp2_(-1.44269504f * accA));     // sigmoid
        float vB = fmaf(aB, rcp_(1.0f + exp2_(sB * accB)), cB); // tanh or sigmoid
        float xA = __shfl_xor(vA, 8);
        float xB = __shfl_xor(vB, 8);
        float iq = half ? xA : vA;
        float gq = half ? xB : vB;
        float fq = half ? vA : xA;
        float oq = half ? vB : xB;
        c0 = fmaf(fq, c0, iq * gq);
        float h0j = oq * tanh_(c0);
        #pragma unroll
        for (int k = 0; k < 8; ++k) h0v[k] = __shfl(h0j, base + k);

        // ---------------- layer 1 ----------------
        accA = bs1A; accB = bs1B;
        #pragma unroll
        for (int k = 0; k < 8; ++k) {
            accA = fmaf(wi1A[k], h0v[k], accA);
            accB = fmaf(wi1B[k], h0v[k], accB);
        }
        #pragma unroll
        for (int k = 0; k < 8; ++k) {
            accA = fmaf(wh1A[k], h1v[k], accA);
            accB = fmaf(wh1B[k], h1v[k], accB);
        }
        vA = rcp_(1.0f + exp2_(-1.44269504f * accA));
        vB = fmaf(aB, rcp_(1.0f + exp2_(sB * accB)), cB);
        xA = __shfl_xor(vA, 8);
        xB = __shfl_xor(vB, 8);
        iq = half ? xA : vA;
        gq = half ? xB : vB;
        fq = half ? vA : xA;
        oq = half ? vB : xB;
        c1 = fmaf(fq, c1, iq * gq);
        float h1j = oq * tanh_(c1);
        #pragma unroll
        for (int k = 0; k < 8; ++k) h1v[k] = __shfl(h1j, base + k);

        // packed-sequence semantics: capture h1 at t == len-1
        ysave = (t == len - 1) ? h1j : ysave;
        #pragma unroll
        for (int k = 0; k < 8; ++k) xf[k] = xn[k];
    }

    if (half == 0) yout[b * 8 + j] = ysave;   // y: [B, 8] fp32 in workspace
}

// heads: feat = tanh(y@Wl.T+bl); value = feat@Wv.T+bv; amean = feat@Wa.T+ba;
// alogstd = broadcast(log_std); astd = exp(log_std)
__global__ __launch_bounds__(256) void heads_kernel(
    const float* __restrict__ y,
    const float* __restrict__ Wl, const float* __restrict__ bl,
    const float* __restrict__ Wv, const float* __restrict__ bv,
    const float* __restrict__ Wa, const float* __restrict__ ba,
    const float* __restrict__ lstd, float* __restrict__ out)
{
    const int b = blockIdx.x * blockDim.x + threadIdx.x;
    if (b >= B_) return;
    float yv[8];
    #pragma unroll
    for (int k = 0; k < 8; ++k) yv[k] = y[b * 8 + k];
    float feat[4];
    #pragma unroll
    for (int l = 0; l < 4; ++l) {
        float acc = bl[l];
        #pragma unroll
        for (int k = 0; k < 8; ++k) acc = fmaf(Wl[l * 8 + k], yv[k], acc);
        feat[l] = tanh_(acc);
    }
    float val = bv[0];
    #pragma unroll
    for (int l = 0; l < 4; ++l) val = fmaf(Wv[l], feat[l], val);
    out[b] = val;                                          // value: [0, 4096)
    #pragma unroll
    for (int a = 0; a < 4; ++a) {
        float am = ba[a];
        #pragma unroll
        for (int l = 0; l < 4; ++l) am = fmaf(Wa[a * 4 + l], feat[l], am);
        out[4096  + b * 4 + a] = am;                       // action_mean
        float ls = lstd[a];
        out[20480 + b * 4 + a] = ls;                       // action_log_std
        out[36864 + b * 4 + a] = exp2_(1.44269504f * ls);  // action_std
    }
}

extern "C" void kernel_launch(void* const* d_in, const int* in_sizes, int n_in,
                              void* d_out, int out_size, void* d_ws, size_t ws_size,
                              hipStream_t stream)
{
    const float* seq   = (const float*)d_in[0];
    const int* lengths = (const int*)d_in[1];
    const float* Wih0  = (const float*)d_in[2];
    const float* Whh0  = (const float*)d_in[3];
    const float* bih0  = (const float*)d_in[4];
    const float* bhh0  = (const float*)d_in[5];
    const float* Wih1  = (const float*)d_in[6];
    const float* Whh1  = (const float*)d_in[7];
    const float* bih1  = (const float*)d_in[8];
    const float* bhh1  = (const float*)d_in[9];
    const float* Wl    = (const float*)d_in[10];
    const float* bl    = (const float*)d_in[11];
    const float* Wv    = (const float*)d_in[12];
    const float* bv    = (const float*)d_in[13];
    const float* Wa    = (const float*)d_in[14];
    const float* ba    = (const float*)d_in[15];
    const float* lstd  = (const float*)d_in[16];

    float* yws = (float*)d_ws;   // [B, 8] fp32

    lstm_main<<<B_ / 4, 64, 0, stream>>>(seq, lengths, Wih0, Whh0, bih0, bhh0,
                                         Wih1, Whh1, bih1, bhh1, yws);
    heads_kernel<<<B_ / 256, 256, 0, stream>>>(yws, Wl, bl, Wv, bv, Wa, ba, lstd,
                                               (float*)d_out);
}

// Round 3
// 899.532 us; speedup vs baseline: 1.5771x; 1.5771x over previous
//
#include <hip/hip_runtime.h>

#define B_ 4096
#define S_ 2048

__device__ __forceinline__ float rcp_(float x)  { return __builtin_amdgcn_rcpf(x); }
__device__ __forceinline__ float exp2_(float x) { return __builtin_amdgcn_exp2f(x); }
// sigmoid(x) = 1/(1+2^(-x*log2e));  tanh(x) = 1 - 2/(1+2^(2x*log2e))
// both saturate cleanly at +-inf (exp2->0 or inf; rcp(inf)=0) — no NaN possible
__device__ __forceinline__ float tanh_(float x) {
    return fmaf(-2.0f, rcp_(1.0f + exp2_(2.88539008f * x)), 1.0f);
}

// DPP cross-lane (VALU, ~2cyc — replaces 120cyc ds_bpermute):
// row_ror:n = 0x120+n, rotates within each 16-lane row.
template<int CTRL>
__device__ __forceinline__ float dppf(float x) {
    int v = __builtin_bit_cast(int, x);
    return __builtin_bit_cast(float,
        __builtin_amdgcn_update_dpp(v, v, CTRL, 0xF, 0xF, false));
}
#define ROR1f dppf<0x121>
#define ROR8f dppf<0x128>
__device__ __forceinline__ int dppi_ror1(int x) {
    return __builtin_amdgcn_update_dpp(x, x, 0x121, 0xF, 0xF, false);
}

__device__ __forceinline__ void ld8(const float* p, float* o) {
    float4 a = *(const float4*)p;
    float4 b = *(const float4*)(p + 4);
    o[0] = a.x; o[1] = a.y; o[2] = a.z; o[3] = a.w;
    o[4] = b.x; o[5] = b.y; o[6] = b.z; o[7] = b.w;
}

// 16 lanes per batch element. sub = lane&15, j = sub&7, half = sub>>3.
// half0 lane owns gate rows i[j] (A) and g~[j] (B); half1 owns f[j] (A), o[j] (B).
// h[j], c[j] computed redundantly in both halves (exchange via DPP ror:8).
// 16-lane h pattern is [h0..h7, h0..h7]; matvec over h uses DPP ror:1 systolic
// rotation with per-lane pre-rotated weights — NO LDS/DS ops in the loop.
__global__ __launch_bounds__(64) void lstm_main(
    const float* __restrict__ seq, const int* __restrict__ lengths,
    const float* __restrict__ Wih0, const float* __restrict__ Whh0,
    const float* __restrict__ bih0, const float* __restrict__ bhh0,
    const float* __restrict__ Wih1, const float* __restrict__ Whh1,
    const float* __restrict__ bih1, const float* __restrict__ bhh1,
    const float* __restrict__ Wl, const float* __restrict__ bl,
    const float* __restrict__ Wv, const float* __restrict__ bv,
    const float* __restrict__ Wa, const float* __restrict__ ba,
    const float* __restrict__ lstd, float* __restrict__ out)
{
    const int tid  = threadIdx.x;
    const int grp  = tid >> 4;
    const int sub  = tid & 15;
    const int j    = sub & 7;
    const int half = sub >> 3;
    const int b    = blockIdx.x * 4 + grp;
    const int base = tid & 48;

    const int gA = half * 8 + j;          // i or f row
    const int gB = 16 + half * 8 + j;     // g~ or o row

    // discover DPP ror:1 direction at runtime (affects only setup indexing)
    const int probe = dppi_ror1(sub);
    const int delta = (sub - probe) & 7;  // 1 or 7: h after k rors = h[(j - k*delta) & 7]

    // x-part weights, natural order (x is held full-vector per lane)
    float wi0A[8], wi0B[8];
    ld8(Wih0 + gA * 8, wi0A);
    ld8(Wih0 + gB * 8, wi0B);
    // h-part weights, pre-rotated to match the DPP rotation stream
    float wh0A[8], wh0B[8], wi1A[8], wi1B[8], wh1A[8], wh1B[8];
    {
        int idx = j;
        #pragma unroll
        for (int k = 0; k < 8; ++k) {
            wh0A[k] = Whh0[gA * 8 + idx];
            wh0B[k] = Whh0[gB * 8 + idx];
            wi1A[k] = Wih1[gA * 8 + idx];
            wi1B[k] = Wih1[gB * 8 + idx];
            wh1A[k] = Whh1[gA * 8 + idx];
            wh1B[k] = Whh1[gB * 8 + idx];
            idx = (idx - delta) & 7;
        }
    }
    const float bs0A = bih0[gA] + bhh0[gA];
    const float bs0B = bih0[gB] + bhh0[gB];
    const float bs1A = bih1[gA] + bhh1[gA];
    const float bs1B = bih1[gB] + bhh1[gB];

    // gate A always sigmoid; gate B: tanh (half0) or sigmoid (half1)
    const float sB = half ? -1.44269504f : 2.88539008f;
    const float aB = half ?  1.0f        : -2.0f;
    const float cB = half ?  0.0f        :  1.0f;

    const int len = lengths[b];
    const int lenm1 = len - 1;
    int maxlen = len;
    maxlen = max(maxlen, __shfl_xor(maxlen, 16));
    maxlen = max(maxlen, __shfl_xor(maxlen, 32));   // wave-uniform loop bound

    float h0j = 0.0f, h1j = 0.0f, c0 = 0.0f, c1 = 0.0f, ysave = 0.0f;

    const float* xbase = seq + (size_t)b * S_ * 8;
    float xf[8], xn[8];
    ld8(xbase, xf);          // t = 0
    ld8(xbase + 8, xn);      // t = 1

    auto step = [&](const float* xv, int t) {
        // ---- layer 0 ----
        float accA = bs0A, accB = bs0B;
        #pragma unroll
        for (int k = 0; k < 8; ++k) {
            accA = fmaf(wi0A[k], xv[k], accA);
            accB = fmaf(wi0B[k], xv[k], accB);
        }
        float r = h0j;
        #pragma unroll
        for (int k = 0; k < 8; ++k) {
            accA = fmaf(wh0A[k], r, accA);
            accB = fmaf(wh0B[k], r, accB);
            if (k < 7) r = ROR1f(r);
        }
        float vA = rcp_(1.0f + exp2_(-1.44269504f * accA));
        float vB = fmaf(aB, rcp_(1.0f + exp2_(sB * accB)), cB);
        float xA = ROR8f(vA), xB = ROR8f(vB);
        float iq = half ? xA : vA, fq = half ? vA : xA;
        float gq = half ? xB : vB, oq = half ? vB : xB;
        c0 = fmaf(fq, c0, iq * gq);
        h0j = oq * tanh_(c0);
        // ---- layer 1 ----  (two rotation streams, parallel partial chains)
        float a1 = bs1A, b1 = bs1B, a2 = 0.0f, b2 = 0.0f;
        float r0 = h0j, r1 = h1j;
        #pragma unroll
        for (int k = 0; k < 8; ++k) {
            a1 = fmaf(wi1A[k], r0, a1);
            b1 = fmaf(wi1B[k], r0, b1);
            a2 = fmaf(wh1A[k], r1, a2);
            b2 = fmaf(wh1B[k], r1, b2);
            if (k < 7) { r0 = ROR1f(r0); r1 = ROR1f(r1); }
        }
        accA = a1 + a2; accB = b1 + b2;
        vA = rcp_(1.0f + exp2_(-1.44269504f * accA));
        vB = fmaf(aB, rcp_(1.0f + exp2_(sB * accB)), cB);
        xA = ROR8f(vA); xB = ROR8f(vB);
        iq = half ? xA : vA; fq = half ? vA : xA;
        gq = half ? xB : vB; oq = half ? vB : xB;
        c1 = fmaf(fq, c1, iq * gq);
        h1j = oq * tanh_(c1);
        ysave = (t == lenm1) ? h1j : ysave;
    };

    // unroll 2: ping-pong x buffers; reload each right after use (overrun past
    // len is harmless: ysave already captured, x reads clamp at S_-1)
    for (int t = 0; t < maxlen; t += 2) {
        step(xf, t);
        ld8(xbase + (size_t)min(t + 2, S_ - 1) * 8, xf);
        step(xn, t + 1);
        ld8(xbase + (size_t)min(t + 3, S_ - 1) * 8, xn);
    }

    // ---- fused heads (once, off the hot loop) ----
    float yv[8];
    #pragma unroll
    for (int k = 0; k < 8; ++k) yv[k] = __shfl(ysave, base + k);
    if (sub == 0) {
        float feat[4];
        #pragma unroll
        for (int l = 0; l < 4; ++l) {
            float acc = bl[l];
            #pragma unroll
            for (int k = 0; k < 8; ++k) acc = fmaf(Wl[l * 8 + k], yv[k], acc);
            feat[l] = tanh_(acc);
        }
        float val = bv[0];
        #pragma unroll
        for (int l = 0; l < 4; ++l) val = fmaf(Wv[l], feat[l], val);
        out[b] = val;                                          // value
        #pragma unroll
        for (int a = 0; a < 4; ++a) {
            float am = ba[a];
            #pragma unroll
            for (int l = 0; l < 4; ++l) am = fmaf(Wa[a * 4 + l], feat[l], am);
            out[4096  + b * 4 + a] = am;                       // action_mean
            float ls = lstd[a];
            out[20480 + b * 4 + a] = ls;                       // action_log_std
            out[36864 + b * 4 + a] = exp2_(1.44269504f * ls);  // action_std
        }
    }
}

extern "C" void kernel_launch(void* const* d_in, const int* in_sizes, int n_in,
                              void* d_out, int out_size, void* d_ws, size_t ws_size,
                              hipStream_t stream)
{
    const float* seq   = (const float*)d_in[0];
    const int* lengths = (const int*)d_in[1];
    const float* Wih0  = (const float*)d_in[2];
    const float* Whh0  = (const float*)d_in[3];
    const float* bih0  = (const float*)d_in[4];
    const float* bhh0  = (const float*)d_in[5];
    const float* Wih1  = (const float*)d_in[6];
    const float* Whh1  = (const float*)d_in[7];
    const float* bih1  = (const float*)d_in[8];
    const float* bhh1  = (const float*)d_in[9];
    const float* Wl    = (const float*)d_in[10];
    const float* bl    = (const float*)d_in[11];
    const float* Wv    = (const float*)d_in[12];
    const float* bv    = (const float*)d_in[13];
    const float* Wa    = (const float*)d_in[14];
    const float* ba    = (const float*)d_in[15];
    const float* lstd  = (const float*)d_in[16];

    lstm_main<<<B_ / 4, 64, 0, stream>>>(seq, lengths, Wih0, Whh0, bih0, bhh0,
                                         Wih1, Whh1, bih1, bhh1,
                                         Wl, bl, Wv, bv, Wa, ba, lstd,
                                         (float*)d_out);
}